// Round 1
// baseline (94.438 us; speedup 1.0000x reference)
//
#include <hip/hip_runtime.h>
#include <math.h>

#define BB 16
#define SS 2048
#define NC 8
#define TILE 256
#define NT (SS/TILE)            // 8 tiles per row
#define TRI (NT*(NT+1)/2)       // 36 (it,jc) tile pairs with jc<=it
#define LOG2E 1.4426950408889634f
#define T1V 100.0f
#define EPSV 1e-8f

__device__ __forceinline__ float fexp2(float x) {
#if __has_builtin(__builtin_amdgcn_exp2f)
    return __builtin_amdgcn_exp2f(x);
#else
    return exp2f(x);
#endif
}

// Kernel A: accumulate K.sum(-1) per event into lam_ws[b*S+i]
__global__ __launch_bounds__(TILE) void hawkes_pairs(
    const float* __restrict__ ts, const int* __restrict__ ms,
    const float* __restrict__ alphas, const float* __restrict__ beta,
    float* __restrict__ lam_ws)
{
    __shared__ float sh_u[TILE];   // p_j * t_j  (or -1e30 if invalid)
    __shared__ float sh_p[TILE];   // beta[m_j] * log2e
    __shared__ int   sh_m[TILE];   // m_j
    __shared__ float sh_ab[NC*NC]; // alphas[r][c]*beta[c]

    int blk = blockIdx.x;
    int b = blk / TRI;
    int r = blk % TRI;
    int it = 0;
    while ((it+1)*(it+2)/2 <= r) ++it;  // triangular decode (r < 36)
    int jc = r - it*(it+1)/2;

    int tid = threadIdx.x;
    if (tid < NC*NC) {
        int row = tid / NC, col = tid % NC;
        sh_ab[tid] = alphas[row*NC+col] * beta[col];
    }

    int jg = jc*TILE + tid;
    float tj = ts[b*SS + jg];
    int   mj = ms[b*SS + jg];
    float pj = beta[mj] * LOG2E;
    sh_u[tid] = (tj > 0.0f) ? pj * tj : -1e30f;  // invalid j -> exp2 -> 0
    sh_p[tid] = pj;
    sh_m[tid] = mj;
    __syncthreads();

    int ig = it*TILE + tid;
    float ti = ts[b*SS + ig];
    int   mi = ms[b*SS + ig];
    const float* abrow = &sh_ab[mi*NC];
    float acc = 0.0f;

    if (jc < it) {
        // full tile: every j < every i
        #pragma unroll 8
        for (int j = 0; j < TILE; ++j) {
            float arg = fmaf(-sh_p[j], ti, sh_u[j]);
            float e   = fexp2(arg);
            acc = fmaf(abrow[sh_m[j]], e, acc);
        }
    } else {
        // diagonal tile: only local j < tid contribute
        #pragma unroll 4
        for (int j = 0; j < TILE; ++j) {
            float arg = fmaf(-sh_p[j], ti, sh_u[j]);
            float e   = fexp2(arg);
            float v   = (j < tid) ? abrow[sh_m[j]] * e : 0.0f;
            acc += v;
        }
    }
    atomicAdd(&lam_ws[b*SS + ig], acc);
}

// Kernel B: sumlog - integ - baserate, reduced into out[0]
__global__ __launch_bounds__(256) void hawkes_finalize(
    const float* __restrict__ ts, const int* __restrict__ ms,
    const float* __restrict__ mu, const float* __restrict__ alphas,
    const float* __restrict__ beta, const float* __restrict__ lam_ws,
    float* __restrict__ out)
{
    __shared__ float sh_acol[NC];
    int tid = threadIdx.x;
    if (tid < NC) {
        float s = 0.0f;
        for (int rr = 0; rr < NC; ++rr) s += alphas[rr*NC + tid];
        sh_acol[tid] = s;   // alphas[:, c].sum(0)
    }
    __syncthreads();

    int idx = blockIdx.x * 256 + tid;   // over B*S
    float t = ts[idx];
    int   m = ms[idx];
    float contrib = 0.0f;
    if (t > 0.0f) {
        float lam = lam_ws[idx] + mu[m];
        contrib = logf(lam + EPSV);
        float tint = 1.0f - fexp2(-beta[m] * LOG2E * (T1V - t));
        contrib -= sh_acol[m] * tint;
    }

    // wave64 reduce then cross-wave
    for (int off = 32; off > 0; off >>= 1)
        contrib += __shfl_down(contrib, off, 64);
    __shared__ float wsum[4];
    int lane = tid & 63, w = tid >> 6;
    if (lane == 0) wsum[w] = contrib;
    __syncthreads();
    if (tid == 0) {
        float s = wsum[0] + wsum[1] + wsum[2] + wsum[3];
        atomicAdd(out, s);
    }
    if (idx == 0) {
        float msum = 0.0f;
        for (int c = 0; c < NC; ++c) msum += mu[c];
        atomicAdd(out, -msum * (T1V - 0.0f));   // baserate
    }
}

extern "C" void kernel_launch(void* const* d_in, const int* in_sizes, int n_in,
                              void* d_out, int out_size, void* d_ws, size_t ws_size,
                              hipStream_t stream) {
    const float* ts     = (const float*)d_in[0];
    const int*   ms     = (const int*)d_in[1];
    const float* mu     = (const float*)d_in[2];
    const float* alphas = (const float*)d_in[3];
    const float* beta   = (const float*)d_in[4];
    float* out    = (float*)d_out;
    float* lam_ws = (float*)d_ws;   // B*S floats

    hipMemsetAsync(lam_ws, 0, BB*SS*sizeof(float), stream);
    hipMemsetAsync(out, 0, sizeof(float), stream);

    hawkes_pairs<<<BB*TRI, TILE, 0, stream>>>(ts, ms, alphas, beta, lam_ws);
    hawkes_finalize<<<(BB*SS)/256, 256, 0, stream>>>(ts, ms, mu, alphas, beta, lam_ws, out);
}

// Round 2
// 76.329 us; speedup vs baseline: 1.2373x; 1.2373x over previous
//
#include <hip/hip_runtime.h>
#include <math.h>

#define BB 16
#define SS 2048
#define NC 8
#define TILE 128
#define NT (SS/TILE)           // 16 tiles per batch row
#define LOG2E 1.4426950408889634f
#define LN2   0.6931471805599453f
#define T1V 100.0f
#define EPSV 1e-8f

__device__ __forceinline__ float fexp2(float x) {
#if __has_builtin(__builtin_amdgcn_exp2f)
    return __builtin_amdgcn_exp2f(x);
#else
    return exp2f(x);
#endif
}
__device__ __forceinline__ float flog2(float x) {
#if __has_builtin(__builtin_amdgcn_logf)
    return __builtin_amdgcn_logf(x);
#else
    return log2f(x);
#endif
}

// Kernel A: per-tile per-class decayed sums
// E[(b*NT+T)*NC+c] = sum_{j in tile T, m_j=c, t_j>0} exp2(p_c*(t_j - tref_T))
// tref_T = ts[b][T*TILE+TILE-1]  (max of tile; ts sorted ascending)
__global__ __launch_bounds__(TILE) void hawkes_tilesum(
    const float* __restrict__ ts, const int* __restrict__ ms,
    const float* __restrict__ beta, float* __restrict__ E)
{
    int b = blockIdx.x / NT;
    int T = blockIdx.x % NT;
    int tid = threadIdx.x;
    int jg = b*SS + T*TILE + tid;

    float tj = ts[jg];
    int   mj = ms[jg];
    float tref = ts[b*SS + T*TILE + TILE-1];
    float p  = beta[mj] * LOG2E;
    float e  = (tj > 0.0f) ? fexp2(p * (tj - tref)) : 0.0f;

    int lane = tid & 63, wave = tid >> 6;
    __shared__ float shw[2*NC];
    #pragma unroll
    for (int c = 0; c < NC; ++c) {
        float v = (mj == c) ? e : 0.0f;
        for (int off = 32; off; off >>= 1) v += __shfl_xor(v, off, 64);
        if (lane == 0) shw[wave*NC + c] = v;
    }
    __syncthreads();
    if (tid < NC) E[(b*NT + T)*NC + tid] = shw[tid] + shw[NC + tid];
}

// Kernel B: everything else, fused. One block per (b, i-tile).
__global__ __launch_bounds__(TILE) void hawkes_main(
    const float* __restrict__ ts, const int* __restrict__ ms,
    const float* __restrict__ mu, const float* __restrict__ alphas,
    const float* __restrict__ beta, const float* __restrict__ E,
    float* __restrict__ out)
{
    int b = blockIdx.x / NT;
    int T = blockIdx.x % NT;
    int tid = threadIdx.x;

    __shared__ float sh_ab[NC*NC];   // alphas[r][c]*beta[c]
    __shared__ float sh_acol[NC];    // alphas[:,c].sum(0)
    __shared__ float sh_pc[NC];      // beta[c]*log2e
    __shared__ float sh_g[NC];       // combined earlier-tile class sums (anchor = tref[T-1])
    __shared__ float sh_pu[TILE];    // p_j*t_j (or -1e30 invalid)
    __shared__ float sh_p[TILE];     // p_j
    __shared__ int   sh_m[TILE];

    if (tid < NC*NC) {
        int col = tid & (NC-1);
        sh_ab[tid] = alphas[tid] * beta[col];
    }
    if (tid < NC) {
        float s = 0.0f;
        #pragma unroll
        for (int r = 0; r < NC; ++r) s += alphas[r*NC + tid];
        sh_acol[tid] = s;
        sh_pc[tid] = beta[tid] * LOG2E;
    }

    int ig = b*SS + T*TILE + tid;
    float ti = ts[ig];
    int   mi = ms[ig];
    float pi = beta[mi] * LOG2E;
    sh_p[tid]  = pi;
    sh_pu[tid] = (ti > 0.0f) ? pi * ti : -1e30f;
    sh_m[tid]  = mi;

    float anchor = (T > 0) ? ts[b*SS + T*TILE - 1] : 0.0f;  // tref of tile T-1
    if (tid < NC) {
        float g = 0.0f;
        if (T > 0) {
            float pc = beta[tid] * LOG2E;
            for (int Tp = 0; Tp < T; ++Tp) {
                float tr = ts[b*SS + Tp*TILE + TILE-1];
                g += fexp2(pc * (tr - anchor)) * E[(b*NT + Tp)*NC + tid];
            }
        }
        sh_g[tid] = g;
    }
    __syncthreads();

    const float* abrow = &sh_ab[mi*NC];
    float acc = 0.0f;

    // cross-tile contribution: 8 classes
    if (T > 0) {
        #pragma unroll
        for (int c = 0; c < NC; ++c) {
            float dec = fexp2(sh_pc[c] * (anchor - ti));   // arg <= 0 (sorted)
            acc = fmaf(abrow[c] * sh_g[c], dec, acc);
        }
    }

    // intra-tile triangle: j < tid
    int wave = tid >> 6, lane = tid & 63;
    int jfull = wave * 64;
    for (int j = 0; j < jfull; ++j) {
        float arg = fmaf(-sh_p[j], ti, sh_pu[j]);
        acc = fmaf(abrow[sh_m[j]], fexp2(arg), acc);
    }
    #pragma unroll 4
    for (int jj = 0; jj < 64; ++jj) {
        int j = jfull + jj;
        float arg = fmaf(-sh_p[j], ti, sh_pu[j]);
        float v = (jj < lane) ? abrow[sh_m[j]] * fexp2(arg) : 0.0f;
        acc += v;
    }

    // finalize this event
    float contrib = 0.0f;
    if (ti > 0.0f) {
        float lam = acc + mu[mi];
        contrib = flog2(lam + EPSV) * LN2;
        float tint = 1.0f - fexp2(-pi * (T1V - ti));
        contrib -= sh_acol[mi] * tint;
    }

    for (int off = 32; off; off >>= 1) contrib += __shfl_xor(contrib, off, 64);
    __shared__ float shred[2];
    if (lane == 0) shred[wave] = contrib;
    __syncthreads();
    if (tid == 0) atomicAdd(out, shred[0] + shred[1]);

    if (blockIdx.x == 0 && tid == 0) {
        float msum = 0.0f;
        #pragma unroll
        for (int c = 0; c < NC; ++c) msum += mu[c];
        atomicAdd(out, -msum * (T1V - 0.0f));
    }
}

extern "C" void kernel_launch(void* const* d_in, const int* in_sizes, int n_in,
                              void* d_out, int out_size, void* d_ws, size_t ws_size,
                              hipStream_t stream) {
    const float* ts     = (const float*)d_in[0];
    const int*   ms     = (const int*)d_in[1];
    const float* mu     = (const float*)d_in[2];
    const float* alphas = (const float*)d_in[3];
    const float* beta   = (const float*)d_in[4];
    float* out = (float*)d_out;
    float* E   = (float*)d_ws;     // BB*NT*NC floats = 2048 floats

    hipMemsetAsync(out, 0, sizeof(float), stream);
    hawkes_tilesum<<<BB*NT, TILE, 0, stream>>>(ts, ms, beta, E);
    hawkes_main<<<BB*NT, TILE, 0, stream>>>(ts, ms, mu, alphas, beta, E, out);
}